// Round 8
// baseline (256.397 us; speedup 1.0000x reference)
//
#include <hip/hip_runtime.h>
#include <stdint.h>

#define TSTEPS 256
#define NB 16
#define NM (TSTEPS*NB)   // 4096

typedef short s16x2 __attribute__((ext_vector_type(2)));

// perm(i) = bitrev8(gray(i)) : the Sobol value rng[i] = 2*perm8(i)/256 - 1
__device__ __forceinline__ uint32_t perm8(int i) {
  uint32_t g = (uint32_t)(i ^ (i >> 1));
  return __brev(g) >> 24;
}

// y = K + sum ashr16(a*t + e, 15): 3 separate asm insts so the scheduler can
// interleave independent chains; t2 is an SGPR (wave-uniform threshold pair).
__device__ __forceinline__ void qstep3s(uint32_t& acc, uint32_t t2, uint32_t a2,
                                        uint32_t e2, uint32_t c15) {
  uint32_t z, z2;
  asm("v_pk_mad_i16 %0, %1, %2, %3" : "=v"(z) : "v"(a2), "s"(t2), "v"(e2));
  asm("v_pk_ashrrev_i16 %0, %1, %2" : "=v"(z2) : "v"(c15), "v"(z));
  asm("v_pk_add_i16 %0, %0, %1" : "+v"(acc) : "v"(z2));
}

// all-VGPR variant (for l3 where T comes from LDS per-lane)
__device__ __forceinline__ void qstep3(uint32_t& acc, uint32_t t2, uint32_t a2,
                                       uint32_t e2, uint32_t c15) {
  uint32_t z;
  asm("v_pk_mad_i16 %0, %2, %3, %4\n\t"
      "v_pk_ashrrev_i16 %0, %5, %0\n\t"
      "v_pk_add_i16 %1, %1, %0"
      : "=&v"(z), "+v"(acc)
      : "v"(a2), "v"(t2), "v"(e2), "v"(c15));
}

__device__ __forceinline__ uint32_t pkadd16(uint32_t a, uint32_t b) {
  return __builtin_bit_cast(uint32_t,
        (s16x2)(__builtin_bit_cast(s16x2, a) + __builtin_bit_cast(s16x2, b)));
}

// unpack packed v16 (u | xbar<<15) pair -> (a2, e2)
__device__ __forceinline__ void unpackAE(uint32_t v2, uint32_t& a2, uint32_t& e2) {
  s16x2 sv = __builtin_bit_cast(s16x2, v2) >> 15;      // 0 / -1 per half (xbar)
  uint32_t su = __builtin_bit_cast(uint32_t, sv);
  uint32_t vand = v2 & 0x01FF01FFu;
  e2 = pkadd16(~vand, su & 0x01FF01FFu);   // x=1: ~u ; x=0: p' = 510-u
  a2 = pkadd16(0x00010001u, pkadd16(su, su));          // +1 / -1
}

__device__ __forceinline__ int rank256(float w) {
  double v = 128.0 * (double)w + 128.0;
  int t = (int)ceil(v);
  if (t < 0) t = 0; if (t > 256) t = 256;
  return t;
}

// ----------------- fused prep: rank tables + bias bitmasks + x chunk sums
// T1/T2 NATURAL layout: T[n][kp] (contiguous per-n rows for s_load).
__global__ __launch_bounds__(256) void k_prepA(
    const float* __restrict__ w1, const float* __restrict__ w2,
    const float* __restrict__ w3, const float* __restrict__ b1,
    const float* __restrict__ b2, const float* __restrict__ b3,
    const int* __restrict__ x,
    uint32_t* __restrict__ T1, uint32_t* __restrict__ T2,
    uint32_t* __restrict__ T3t, uint32_t* __restrict__ bb1,
    uint32_t* __restrict__ bb2, uint32_t* __restrict__ bb3,
    uint16_t* __restrict__ cs)
{
  int bid = blockIdx.x, tid = threadIdx.x;
  if (bid < 1024) {                      // w1 -> T1 [512 n][512 kp]
    int e = bid * 256 + tid;
    T1[e] = (uint32_t)rank256(w1[2 * e]) |
            ((uint32_t)rank256(w1[2 * e + 1]) << 16);
  } else if (bid < 1280) {               // w2 -> T2 [256 n][256 kp]
    int e = (bid - 1024) * 256 + tid;
    T2[e] = (uint32_t)rank256(w2[2 * e]) |
            ((uint32_t)rank256(w2[2 * e + 1]) << 16);
  } else if (bid < 1285) {               // w3 -> T3t [128 kp][10 n]
    int e = (bid - 1280) * 256 + tid;
    if (e < 1280) {
      int n = e % 10, kp = e / 10;
      T3t[e] = (uint32_t)rank256(w3[n * 256 + 2 * kp]) |
               ((uint32_t)rank256(w3[n * 256 + 2 * kp + 1]) << 16);
    }
  } else if (bid < 1301) {               // bb1: 512 o x 8 words
    int w = (bid - 1285) * 256 + tid;
    int o = w >> 3, j = w & 7;
    double bv = (double)b1[o] * 128.0 + 128.0;
    uint32_t bits = 0;
    for (int s = 0; s < 32; ++s)
      if (bv > (double)perm8(j * 32 + s)) bits |= 1u << s;
    bb1[w] = bits;
  } else if (bid < 1309) {               // bb2: 256 o x 8 words
    int w = (bid - 1301) * 256 + tid;
    int o = w >> 3, j = w & 7;
    double bv = (double)b2[o] * 128.0 + 128.0;
    uint32_t bits = 0;
    for (int s = 0; s < 32; ++s)
      if (bv > (double)perm8(j * 32 + s)) bits |= 1u << s;
    bb2[w] = bits;
  } else if (bid == 1309) {              // bb3: 10 o x 8 words
    if (tid < 80) {
      int o = tid >> 3, j = tid & 7;
      double bv = (double)b3[o] * 128.0 + 128.0;
      uint32_t bits = 0;
      for (int s = 0; s < 32; ++s)
        if (bv > (double)perm8(j * 32 + s)) bits |= 1u << s;
      bb3[tid] = bits;
    }
  } else {                               // x chunk sums (512 blocks)
    int g = (bid - 1310) * 256 + tid;
    int i = g & 1023, b = (g >> 10) & 15, c = g >> 14;
    int s = 0, t0 = c * 32;
    for (int tt = t0; tt < t0 + 32; ++tt)
      s += x[((size_t)tt * NB + b) * 1024 + i];
    cs[(c * NB + b) * 1024 + i] = (uint16_t)s;
  }
}

// -------------------------------- layer-1 V build (m = b*256+t, b-major)
__global__ __launch_bounds__(256) void k_prep1(const int* __restrict__ x,
                                               const uint16_t* __restrict__ cs,
                                               uint16_t* __restrict__ V1) {
  int g = blockIdx.x * 256 + threadIdx.x;
  int i = g & 1023, b = (g >> 10) & 15, c = g >> 14;
  int cum = 0;
  for (int cc = 0; cc < c; ++cc) cum += cs[(cc * NB + b) * 1024 + i];
  int t0 = c * 32;
  for (int tt = t0; tt < t0 + 32; ++tt) {
    int m = b * 256 + tt;
    int xv = x[((size_t)tt * NB + b) * 1024 + i];
    int idx = xv ? cum : (tt - cum);
    uint32_t p = perm8(idx);
    V1[(size_t)m * 1024 + i] =
        (uint16_t)((xv ? p : (510u - p)) | ((uint32_t)(xv ^ 1) << 15));
    cum += xv;
  }
}

// ---------------- scalar-pipe binary GEMM: U resident in VGPRs, T via s_load.
// __launch_bounds__(256, 4): allow ~128 VGPRs so a2/e2 arrays STAY RESIDENT
// (with the default bound the compiler remat'ed the unpack inside the n-loop
// — R7's 2.15x VALU inflation). T row batched -> one s_load group + one wait.
template<int KD, int NT, int NPB, int KC>
__global__ __launch_bounds__(256, 4) void k_gemmv3(
    const uint16_t* __restrict__ V, const uint32_t* __restrict__ T,
    uint8_t* __restrict__ Yp)
{
  constexpr int KP = KC / 2;
  const int tid = threadIdx.x;
  const int m = blockIdx.x * 256 + tid;
  const int n0 = blockIdx.y * NPB;
  const int sk = blockIdx.z;
  const int k0 = sk * KC;
  uint32_t a2[KP], e2[KP];
  {
    const uint4* src = (const uint4*)(V + (size_t)m * KD + k0);
    #pragma unroll
    for (int q = 0; q < KC / 8; ++q) {
      uint4 vv = src[q];
      unpackAE(vv.x, a2[q * 4 + 0], e2[q * 4 + 0]);
      unpackAE(vv.y, a2[q * 4 + 1], e2[q * 4 + 1]);
      unpackAE(vv.z, a2[q * 4 + 2], e2[q * 4 + 2]);
      unpackAE(vv.w, a2[q * 4 + 3], e2[q * 4 + 3]);
    }
  }
  const uint32_t c15 = 0x000F000Fu;
  uint8_t* outp = Yp + ((size_t)sk * NT + n0) * (size_t)NM + m;
  for (int n = 0; n < NPB; ++n) {
    const uint4* tr = (const uint4*)(T + (size_t)(n0 + n) * (KD / 2) + (k0 >> 1));
    uint4 trow[KP / 4];
    #pragma unroll
    for (int j = 0; j < KP / 4; ++j) trow[j] = tr[j];  // uniform -> s_load batch
    uint32_t q0 = 0, q1 = 0, q2 = 0, q3 = 0;
    #pragma unroll
    for (int j = 0; j < KP / 4; ++j) {
      qstep3s(q0, trow[j].x, a2[j * 4 + 0], e2[j * 4 + 0], c15);
      qstep3s(q1, trow[j].y, a2[j * 4 + 1], e2[j * 4 + 1], c15);
      qstep3s(q2, trow[j].z, a2[j * 4 + 2], e2[j * 4 + 2], c15);
      qstep3s(q3, trow[j].w, a2[j * 4 + 3], e2[j * 4 + 3], c15);
    }
    uint32_t s = pkadd16(pkadd16(q0, q1), pkadd16(q2, q3));
    int cnt = KC + (int)(short)(s & 0xFFFFu) + (int)(short)(s >> 16);
    outp[(size_t)n * NM] = (uint8_t)cnt;
  }
}

// ------------------- sum 16 u8 split-K planes -> u16 counts [n][m]
__global__ __launch_bounds__(256) void k_sumY(
    const uint8_t* __restrict__ Yp, uint16_t* __restrict__ Ys,
    int nwords, size_t plane_words)
{
  int i = blockIdx.x * 256 + threadIdx.x;
  if (i >= nwords) return;
  const uint32_t* p = (const uint32_t*)Yp;
  uint32_t aL = 0, aH = 0;
  for (int s = 0; s < 16; ++s) {
    uint32_t w = p[(size_t)s * plane_words + i];
    aL = pkadd16(aL, w & 0x00FF00FFu);
    aH = pkadd16(aH, (w >> 8) & 0x00FF00FFu);
  }
  uint2 o;
  o.x = (aL & 0xFFFFu) | (aH << 16);
  o.y = (aL >> 16) | (aH & 0xFFFF0000u);
  ((uint2*)Ys)[i] = o;
}

// ---------------- integer scan (ulinear + ucompare) -> next-layer V
template<int NOUT, int OFF2, int LOGN>
__global__ __launch_bounds__(64) void k_scanv2(
    const uint16_t* __restrict__ Ys, const uint32_t* __restrict__ bb,
    uint16_t* __restrict__ Vn)
{
  int g = blockIdx.x * 64 + threadIdx.x;
  int o = g & (NOUT - 1);
  int b = g >> LOGN;
  const uint16_t* row = Ys + (size_t)o * NM + b * 256;
  int in2 = 0, out2 = 0, c2 = 0, cum = 0;
  uint4 cur = *(const uint4*)row;
  #pragma unroll
  for (int w = 0; w < 8; ++w) {
    uint32_t bwc = bb[o * 8 + w];
    #pragma unroll
    for (int cchunk = 0; cchunk < 4; ++cchunk) {
      int t0 = w * 32 + cchunk * 8;
      uint4 nxt = cur;
      if (t0 < 248) nxt = *(const uint4*)(row + t0 + 8);
      uint32_t cw[4] = {cur.x, cur.y, cur.z, cur.w};
      #pragma unroll
      for (int j = 0; j < 8; ++j) {
        int t = t0 + j;
        int cnt = (int)((cw[j >> 1] >> ((j & 1) * 16)) & 0xFFFFu);
        int bit = (int)((bwc >> (t & 31)) & 1u);
        in2 += 2 * cnt + 2 * bit - OFF2;
        int outb = (in2 > out2) ? 1 : 0;
        out2 += outb << 1;
        int a = (c2 < 0) ? 1 : outb;
        c2 += (a << 2) - 2;
        int idx = a ? cum : (t - cum);
        cum += a;
        uint32_t p = perm8(idx);
        Vn[(size_t)(b * 256 + t) * NOUT + o] =
            (uint16_t)((a ? p : (510u - p)) | ((uint32_t)(a ^ 1) << 15));
      }
      cur = nxt;
    }
  }
}

// ------------------------------------------------------------ layer 3 (OUT=10)
__global__ __launch_bounds__(256) void k_l3(
    const uint16_t* __restrict__ V3, const uint32_t* __restrict__ T3t,
    uint16_t* __restrict__ y3)
{
  __shared__ uint32_t T3s[128][16];    // [kp][o]
  __shared__ uint32_t UFs3[16][258];   // [m][2*kp + {a,e}]
  int tid = threadIdx.x;
  int m0 = blockIdx.x * 16;
  const uint32_t c15 = 0x000F000Fu;
  for (int j = tid; j < 2048; j += 256) {
    int kp = j >> 4, o2 = j & 15;
    T3s[kp][o2] = (o2 < 10) ? T3t[kp * 10 + o2] : 0u;
  }
  { int row = tid >> 4, part = tid & 15;
    const uint4* src = (const uint4*)(V3 + (size_t)(m0 + row) * 256 + part * 16);
    uint4 pa = src[0], pb = src[1];
    uint32_t w[8] = {pa.x, pa.y, pa.z, pa.w, pb.x, pb.y, pb.z, pb.w};
    uint32_t o[16];
    #pragma unroll
    for (int q = 0; q < 8; ++q) unpackAE(w[q], o[q * 2], o[q * 2 + 1]);
    #pragma unroll
    for (int q4 = 0; q4 < 4; ++q4)
      *(uint4*)&UFs3[row][part * 16 + q4 * 4] =
          make_uint4(o[q4 * 4], o[q4 * 4 + 1], o[q4 * 4 + 2], o[q4 * 4 + 3]);
  }
  __syncthreads();
  int mr = tid >> 4, o = tid & 15;
  uint32_t acc = 0;
  #pragma unroll 4
  for (int kp2 = 0; kp2 < 64; ++kp2) {
    uint4 uf = *(const uint4*)&UFs3[mr][kp2 * 4];
    qstep3(acc, T3s[2 * kp2][o],     uf.x, uf.y, c15);
    qstep3(acc, T3s[2 * kp2 + 1][o], uf.z, uf.w, c15);
  }
  if (o < 10)
    y3[(size_t)(m0 + mr) * 16 + o] =
        (uint16_t)(256 + (short)(acc & 0xFFFFu) + (short)(acc >> 16));
}

// ---------------- layer-3 scan (bit-matrix in LDS) + log_softmax, fused
__global__ __launch_bounds__(256) void k_scan3sm(
    const uint16_t* __restrict__ y3, const uint32_t* __restrict__ bb3,
    const float* __restrict__ pred, float* __restrict__ out)
{
  __shared__ uint32_t obl[16][16][8];
  __shared__ float prs[160];
  int tid = threadIdx.x;
  if (tid < 160) prs[tid] = pred[tid];
  int b = tid >> 4, o = tid & 15;
  if (o < 10) {
    const uint16_t* row = y3 + (size_t)b * 256 * 16 + o;
    int in2 = 0, out2 = 0;
    #pragma unroll
    for (int w = 0; w < 8; ++w) {
      uint32_t bwc = bb3[o * 8 + w];
      uint32_t bits = 0;
      for (int s = 0; s < 32; ++s) {
        int cnt = row[(w * 32 + s) * 16];
        in2 += 2 * cnt + 2 * (int)((bwc >> s) & 1u) - 255;
        int outb = (in2 > out2) ? 1 : 0;
        out2 += outb << 1;
        bits |= (uint32_t)outb << s;
      }
      obl[b][o][w] = bits;
    }
  }
  __syncthreads();
  for (int r = tid; r < 4096; r += 256) {
    int t = r >> 4, b2 = r & 15;
    float z[10], mx = -3e38f;
    #pragma unroll
    for (int oo = 0; oo < 10; ++oo) {
      int bit = (obl[b2][oo][t >> 5] >> (t & 31)) & 1;
      z[oo] = (bit ? 1.f : -1.f) - prs[b2 * 10 + oo];
      mx = fmaxf(mx, z[oo]);
    }
    float s = 0.f;
    #pragma unroll
    for (int oo = 0; oo < 10; ++oo) s += expf(z[oo] - mx);
    float ls = logf(s);
    float* op = out + (size_t)r * 10;       // r = t*16+b  ==  (t*NB+b)
    #pragma unroll
    for (int oo = 0; oo < 10; ++oo) op[oo] = z[oo] - mx - ls;
  }
}

// ---------------------------------------------------------------------------
extern "C" void kernel_launch(void* const* d_in, const int* in_sizes, int n_in,
                              void* d_out, int out_size, void* d_ws, size_t ws_size,
                              hipStream_t stream) {
  (void)in_sizes; (void)n_in; (void)out_size; (void)ws_size;
  const float* w1   = (const float*)d_in[0];
  const float* b1   = (const float*)d_in[1];
  const float* w2   = (const float*)d_in[2];
  const float* b2   = (const float*)d_in[3];
  const float* w3   = (const float*)d_in[4];
  const float* b3   = (const float*)d_in[5];
  const float* pred = (const float*)d_in[6];
  const int*   x    = (const int*)d_in[7];
  float* out = (float*)d_out;
  uint8_t* W = (uint8_t*)d_ws;

  uint32_t* T1   = (uint32_t*)(W + 0);          // 1 MB  [512 n][512 kp]
  uint32_t* T2   = (uint32_t*)(W + 1048576);    // 256 KB [256 n][256 kp]
  uint32_t* T3t  = (uint32_t*)(W + 1310720);    // 8 KB  [128 kp][10 n]
  uint32_t* bb1  = (uint32_t*)(W + 1318912);    // 16 KB
  uint32_t* bb2  = (uint32_t*)(W + 1335296);    // 8 KB
  uint32_t* bb3  = (uint32_t*)(W + 1343488);    // 512 B
  uint16_t* chks = (uint16_t*)(W + 1344000);    // 256 KB          end 1606144
  // V1 region (8 MB), dead after gemm1:
  uint16_t* V1   = (uint16_t*)(W + 1606144);
  uint16_t* Ys1  = (uint16_t*)(W + 1606144);    // 4 MB (alias, after gemm1)
  uint16_t* V2   = (uint16_t*)(W + 5800448);    // 4 MB
  // Yp region (33.55 MB):
  uint8_t*  Yp1  = (uint8_t*) (W + 9994752);    // 16 x 2 MB u8
  uint8_t*  Yp2  = (uint8_t*) (W + 9994752);    // 16 x 1 MB u8 (alias)
  uint16_t* Ys2  = (uint16_t*)(W + 26771968);   // 2 MB
  uint16_t* V3   = (uint16_t*)(W + 28869120);   // 2 MB
  uint16_t* Y3   = (uint16_t*)(W + 30966272);   // 128 KB
  // peak end = 43,549,184 bytes (proven available in R5/R6/R7)

  hipLaunchKernelGGL(k_prepA, dim3(1822), dim3(256), 0, stream,
                     w1, w2, w3, b1, b2, b3, x, T1, T2, T3t, bb1, bb2, bb3, chks);
  hipLaunchKernelGGL(k_prep1, dim3(512), dim3(256), 0, stream, x, chks, V1);
  hipLaunchKernelGGL((k_gemmv3<1024, 512, 128, 64>), dim3(16, 4, 16), dim3(256),
                     0, stream, V1, T1, Yp1);
  hipLaunchKernelGGL(k_sumY, dim3(2048), dim3(256), 0, stream,
                     Yp1, Ys1, 512 * NM / 4, (size_t)(512 * NM / 4));
  hipLaunchKernelGGL((k_scanv2<512, 1023, 9>), dim3(128), dim3(64), 0, stream,
                     Ys1, bb1, V2);
  hipLaunchKernelGGL((k_gemmv3<512, 256, 64, 32>), dim3(16, 4, 16), dim3(256),
                     0, stream, V2, T2, Yp2);
  hipLaunchKernelGGL(k_sumY, dim3(1024), dim3(256), 0, stream,
                     Yp2, Ys2, 256 * NM / 4, (size_t)(256 * NM / 4));
  hipLaunchKernelGGL((k_scanv2<256, 511, 8>), dim3(64), dim3(64), 0, stream,
                     Ys2, bb2, V3);
  hipLaunchKernelGGL(k_l3, dim3(256), dim3(256), 0, stream, V3, T3t, Y3);
  hipLaunchKernelGGL(k_scan3sm, dim3(1), dim3(256), 0, stream, Y3, bb3, pred, out);
}

// Round 9
// 244.026 us; speedup vs baseline: 1.0507x; 1.0507x over previous
//
#include <hip/hip_runtime.h>
#include <stdint.h>

#define TSTEPS 256
#define NB 16
#define NM (TSTEPS*NB)   // 4096

typedef short s16x2 __attribute__((ext_vector_type(2)));

// perm(i) = bitrev8(gray(i)) : the Sobol value rng[i] = 2*perm8(i)/256 - 1
__device__ __forceinline__ uint32_t perm8(int i) {
  uint32_t g = (uint32_t)(i ^ (i >> 1));
  return __brev(g) >> 24;
}

// y = K + sum ashr16(a*t + e, 15): 3 separate asm insts so the scheduler can
// interleave independent chains; t2 is an SGPR (wave-uniform threshold pair).
__device__ __forceinline__ void qstep3s(uint32_t& acc, uint32_t t2, uint32_t a2,
                                        uint32_t e2, uint32_t c15) {
  uint32_t z, z2;
  asm("v_pk_mad_i16 %0, %1, %2, %3" : "=v"(z) : "v"(a2), "s"(t2), "v"(e2));
  asm("v_pk_ashrrev_i16 %0, %1, %2" : "=v"(z2) : "v"(c15), "v"(z));
  asm("v_pk_add_i16 %0, %0, %1" : "+v"(acc) : "v"(z2));
}

// all-VGPR variant (for l3 where T comes from LDS per-lane)
__device__ __forceinline__ void qstep3(uint32_t& acc, uint32_t t2, uint32_t a2,
                                       uint32_t e2, uint32_t c15) {
  uint32_t z;
  asm("v_pk_mad_i16 %0, %2, %3, %4\n\t"
      "v_pk_ashrrev_i16 %0, %5, %0\n\t"
      "v_pk_add_i16 %1, %1, %0"
      : "=&v"(z), "+v"(acc)
      : "v"(a2), "v"(t2), "v"(e2), "v"(c15));
}

__device__ __forceinline__ uint32_t pkadd16(uint32_t a, uint32_t b) {
  return __builtin_bit_cast(uint32_t,
        (s16x2)(__builtin_bit_cast(s16x2, a) + __builtin_bit_cast(s16x2, b)));
}

// unpack packed v16 (u | xbar<<15) pair -> (a2, e2)
__device__ __forceinline__ void unpackAE(uint32_t v2, uint32_t& a2, uint32_t& e2) {
  s16x2 sv = __builtin_bit_cast(s16x2, v2) >> 15;      // 0 / -1 per half (xbar)
  uint32_t su = __builtin_bit_cast(uint32_t, sv);
  uint32_t vand = v2 & 0x01FF01FFu;
  e2 = pkadd16(~vand, su & 0x01FF01FFu);   // x=1: ~u ; x=0: p' = 510-u
  a2 = pkadd16(0x00010001u, pkadd16(su, su));          // +1 / -1
}

__device__ __forceinline__ int rank256(float w) {
  double v = 128.0 * (double)w + 128.0;
  int t = (int)ceil(v);
  if (t < 0) t = 0; if (t > 256) t = 256;
  return t;
}

// ----------------- fused prep: rank tables + bias bitmasks + x chunk sums
// T1/T2 NATURAL layout: T[n][kp] (contiguous per-n rows for s_load).
__global__ __launch_bounds__(256) void k_prepA(
    const float* __restrict__ w1, const float* __restrict__ w2,
    const float* __restrict__ w3, const float* __restrict__ b1,
    const float* __restrict__ b2, const float* __restrict__ b3,
    const int* __restrict__ x,
    uint32_t* __restrict__ T1, uint32_t* __restrict__ T2,
    uint32_t* __restrict__ T3t, uint32_t* __restrict__ bb1,
    uint32_t* __restrict__ bb2, uint32_t* __restrict__ bb3,
    uint16_t* __restrict__ cs)
{
  int bid = blockIdx.x, tid = threadIdx.x;
  if (bid < 1024) {                      // w1 -> T1 [512 n][512 kp]
    int e = bid * 256 + tid;
    T1[e] = (uint32_t)rank256(w1[2 * e]) |
            ((uint32_t)rank256(w1[2 * e + 1]) << 16);
  } else if (bid < 1280) {               // w2 -> T2 [256 n][256 kp]
    int e = (bid - 1024) * 256 + tid;
    T2[e] = (uint32_t)rank256(w2[2 * e]) |
            ((uint32_t)rank256(w2[2 * e + 1]) << 16);
  } else if (bid < 1285) {               // w3 -> T3t [128 kp][10 n]
    int e = (bid - 1280) * 256 + tid;
    if (e < 1280) {
      int n = e % 10, kp = e / 10;
      T3t[e] = (uint32_t)rank256(w3[n * 256 + 2 * kp]) |
               ((uint32_t)rank256(w3[n * 256 + 2 * kp + 1]) << 16);
    }
  } else if (bid < 1301) {               // bb1: 512 o x 8 words
    int w = (bid - 1285) * 256 + tid;
    int o = w >> 3, j = w & 7;
    double bv = (double)b1[o] * 128.0 + 128.0;
    uint32_t bits = 0;
    for (int s = 0; s < 32; ++s)
      if (bv > (double)perm8(j * 32 + s)) bits |= 1u << s;
    bb1[w] = bits;
  } else if (bid < 1309) {               // bb2: 256 o x 8 words
    int w = (bid - 1301) * 256 + tid;
    int o = w >> 3, j = w & 7;
    double bv = (double)b2[o] * 128.0 + 128.0;
    uint32_t bits = 0;
    for (int s = 0; s < 32; ++s)
      if (bv > (double)perm8(j * 32 + s)) bits |= 1u << s;
    bb2[w] = bits;
  } else if (bid == 1309) {              // bb3: 10 o x 8 words
    if (tid < 80) {
      int o = tid >> 3, j = tid & 7;
      double bv = (double)b3[o] * 128.0 + 128.0;
      uint32_t bits = 0;
      for (int s = 0; s < 32; ++s)
        if (bv > (double)perm8(j * 32 + s)) bits |= 1u << s;
      bb3[tid] = bits;
    }
  } else {                               // x chunk sums (512 blocks)
    int g = (bid - 1310) * 256 + tid;
    int i = g & 1023, b = (g >> 10) & 15, c = g >> 14;
    int s = 0, t0 = c * 32;
    for (int tt = t0; tt < t0 + 32; ++tt)
      s += x[((size_t)tt * NB + b) * 1024 + i];
    cs[(c * NB + b) * 1024 + i] = (uint16_t)s;
  }
}

// -------------------------------- layer-1 V build (m = b*256+t, b-major)
__global__ __launch_bounds__(256) void k_prep1(const int* __restrict__ x,
                                               const uint16_t* __restrict__ cs,
                                               uint16_t* __restrict__ V1) {
  int g = blockIdx.x * 256 + threadIdx.x;
  int i = g & 1023, b = (g >> 10) & 15, c = g >> 14;
  int cum = 0;
  for (int cc = 0; cc < c; ++cc) cum += cs[(cc * NB + b) * 1024 + i];
  int t0 = c * 32;
  for (int tt = t0; tt < t0 + 32; ++tt) {
    int m = b * 256 + tt;
    int xv = x[((size_t)tt * NB + b) * 1024 + i];
    int idx = xv ? cum : (tt - cum);
    uint32_t p = perm8(idx);
    V1[(size_t)m * 1024 + i] =
        (uint16_t)((xv ? p : (510u - p)) | ((uint32_t)(xv ^ 1) << 15));
    cum += xv;
  }
}

// ---------------- k-outer binary GEMM: NREG n-accumulators resident,
// V unpacked per 8-element chunk (short-lived, amortized over NREG n's),
// T via uniform s_load_dwordx4 feeding v_pk_mad's SGPR operand. No LDS.
// Yp[sk][n][m] u8 = exact count over this KC chunk (KC<=128 -> fits u8 * wait,
// per-half range is [-KC/2,0], cnt in [0,KC] <= 128, fits).
template<int KD, int NT, int NREG, int KC>
__global__ __launch_bounds__(256, 4) void k_gemmv4(
    const uint16_t* __restrict__ V, const uint32_t* __restrict__ T,
    uint8_t* __restrict__ Yp)
{
  const int tid = threadIdx.x;
  const int m = blockIdx.x * 256 + tid;
  const int n0 = blockIdx.y * NREG;
  const int sk = blockIdx.z;
  const int k0 = sk * KC;
  const uint32_t c15 = 0x000F000Fu;
  uint32_t acc[NREG];
  #pragma unroll
  for (int nn = 0; nn < NREG; ++nn) acc[nn] = 0;
  const uint4* vsrc = (const uint4*)(V + (size_t)m * KD + k0);
  const uint32_t* tbase = T + (size_t)n0 * (KD / 2) + (k0 >> 1);
  #pragma unroll 2
  for (int c = 0; c < KC / 8; ++c) {
    uint4 vv = vsrc[c];
    uint32_t a0, e0, a1, e1, a2v, e2v, a3, e3;
    unpackAE(vv.x, a0, e0);
    unpackAE(vv.y, a1, e1);
    unpackAE(vv.z, a2v, e2v);
    unpackAE(vv.w, a3, e3);
    #pragma unroll
    for (int nn = 0; nn < NREG; ++nn) {
      uint4 tw = *(const uint4*)(tbase + (size_t)nn * (KD / 2) + c * 4);
      qstep3s(acc[nn], tw.x, a0, e0, c15);
      qstep3s(acc[nn], tw.y, a1, e1, c15);
      qstep3s(acc[nn], tw.z, a2v, e2v, c15);
      qstep3s(acc[nn], tw.w, a3, e3, c15);
    }
  }
  uint8_t* outp = Yp + ((size_t)sk * NT + n0) * (size_t)NM + m;
  #pragma unroll
  for (int nn = 0; nn < NREG; ++nn) {
    uint32_t s = acc[nn];
    int cnt = KC + (int)(short)(s & 0xFFFFu) + (int)(short)(s >> 16);
    outp[(size_t)nn * NM] = (uint8_t)cnt;
  }
}

// ------------------- sum SK u8 split-K planes -> u16 counts [n][m]
__global__ __launch_bounds__(256) void k_sumY(
    const uint8_t* __restrict__ Yp, uint16_t* __restrict__ Ys,
    int nwords, size_t plane_words, int SK)
{
  int i = blockIdx.x * 256 + threadIdx.x;
  if (i >= nwords) return;
  const uint32_t* p = (const uint32_t*)Yp;
  uint32_t aL = 0, aH = 0;
  for (int s = 0; s < SK; ++s) {
    uint32_t w = p[(size_t)s * plane_words + i];
    aL = pkadd16(aL, w & 0x00FF00FFu);
    aH = pkadd16(aH, (w >> 8) & 0x00FF00FFu);
  }
  uint2 o;
  o.x = (aL & 0xFFFFu) | (aH << 16);
  o.y = (aL >> 16) | (aH & 0xFFFF0000u);
  ((uint2*)Ys)[i] = o;
}

// ---------------- integer scan (ulinear + ucompare) -> next-layer V
template<int NOUT, int OFF2, int LOGN>
__global__ __launch_bounds__(64) void k_scanv2(
    const uint16_t* __restrict__ Ys, const uint32_t* __restrict__ bb,
    uint16_t* __restrict__ Vn)
{
  int g = blockIdx.x * 64 + threadIdx.x;
  int o = g & (NOUT - 1);
  int b = g >> LOGN;
  const uint16_t* row = Ys + (size_t)o * NM + b * 256;
  int in2 = 0, out2 = 0, c2 = 0, cum = 0;
  uint4 cur = *(const uint4*)row;
  #pragma unroll
  for (int w = 0; w < 8; ++w) {
    uint32_t bwc = bb[o * 8 + w];
    #pragma unroll
    for (int cchunk = 0; cchunk < 4; ++cchunk) {
      int t0 = w * 32 + cchunk * 8;
      uint4 nxt = cur;
      if (t0 < 248) nxt = *(const uint4*)(row + t0 + 8);
      uint32_t cw[4] = {cur.x, cur.y, cur.z, cur.w};
      #pragma unroll
      for (int j = 0; j < 8; ++j) {
        int t = t0 + j;
        int cnt = (int)((cw[j >> 1] >> ((j & 1) * 16)) & 0xFFFFu);
        int bit = (int)((bwc >> (t & 31)) & 1u);
        in2 += 2 * cnt + 2 * bit - OFF2;
        int outb = (in2 > out2) ? 1 : 0;
        out2 += outb << 1;
        int a = (c2 < 0) ? 1 : outb;
        c2 += (a << 2) - 2;
        int idx = a ? cum : (t - cum);
        cum += a;
        uint32_t p = perm8(idx);
        Vn[(size_t)(b * 256 + t) * NOUT + o] =
            (uint16_t)((a ? p : (510u - p)) | ((uint32_t)(a ^ 1) << 15));
      }
      cur = nxt;
    }
  }
}

// ------------------------------------------------------------ layer 3 (OUT=10)
__global__ __launch_bounds__(256) void k_l3(
    const uint16_t* __restrict__ V3, const uint32_t* __restrict__ T3t,
    uint16_t* __restrict__ y3)
{
  __shared__ uint32_t T3s[128][16];    // [kp][o]
  __shared__ uint32_t UFs3[16][258];   // [m][2*kp + {a,e}]
  int tid = threadIdx.x;
  int m0 = blockIdx.x * 16;
  const uint32_t c15 = 0x000F000Fu;
  for (int j = tid; j < 2048; j += 256) {
    int kp = j >> 4, o2 = j & 15;
    T3s[kp][o2] = (o2 < 10) ? T3t[kp * 10 + o2] : 0u;
  }
  { int row = tid >> 4, part = tid & 15;
    const uint4* src = (const uint4*)(V3 + (size_t)(m0 + row) * 256 + part * 16);
    uint4 pa = src[0], pb = src[1];
    uint32_t w[8] = {pa.x, pa.y, pa.z, pa.w, pb.x, pb.y, pb.z, pb.w};
    uint32_t o[16];
    #pragma unroll
    for (int q = 0; q < 8; ++q) unpackAE(w[q], o[q * 2], o[q * 2 + 1]);
    #pragma unroll
    for (int q4 = 0; q4 < 4; ++q4)
      *(uint4*)&UFs3[row][part * 16 + q4 * 4] =
          make_uint4(o[q4 * 4], o[q4 * 4 + 1], o[q4 * 4 + 2], o[q4 * 4 + 3]);
  }
  __syncthreads();
  int mr = tid >> 4, o = tid & 15;
  uint32_t acc = 0;
  #pragma unroll 4
  for (int kp2 = 0; kp2 < 64; ++kp2) {
    uint4 uf = *(const uint4*)&UFs3[mr][kp2 * 4];
    qstep3(acc, T3s[2 * kp2][o],     uf.x, uf.y, c15);
    qstep3(acc, T3s[2 * kp2 + 1][o], uf.z, uf.w, c15);
  }
  if (o < 10)
    y3[(size_t)(m0 + mr) * 16 + o] =
        (uint16_t)(256 + (short)(acc & 0xFFFFu) + (short)(acc >> 16));
}

// ---------------- layer-3 scan (bit-matrix in LDS) + log_softmax, fused
__global__ __launch_bounds__(256) void k_scan3sm(
    const uint16_t* __restrict__ y3, const uint32_t* __restrict__ bb3,
    const float* __restrict__ pred, float* __restrict__ out)
{
  __shared__ uint32_t obl[16][16][8];
  __shared__ float prs[160];
  int tid = threadIdx.x;
  if (tid < 160) prs[tid] = pred[tid];
  int b = tid >> 4, o = tid & 15;
  if (o < 10) {
    const uint16_t* row = y3 + (size_t)b * 256 * 16 + o;
    int in2 = 0, out2 = 0;
    #pragma unroll
    for (int w = 0; w < 8; ++w) {
      uint32_t bwc = bb3[o * 8 + w];
      uint32_t bits = 0;
      for (int s = 0; s < 32; ++s) {
        int cnt = row[(w * 32 + s) * 16];
        in2 += 2 * cnt + 2 * (int)((bwc >> s) & 1u) - 255;
        int outb = (in2 > out2) ? 1 : 0;
        out2 += outb << 1;
        bits |= (uint32_t)outb << s;
      }
      obl[b][o][w] = bits;
    }
  }
  __syncthreads();
  for (int r = tid; r < 4096; r += 256) {
    int t = r >> 4, b2 = r & 15;
    float z[10], mx = -3e38f;
    #pragma unroll
    for (int oo = 0; oo < 10; ++oo) {
      int bit = (obl[b2][oo][t >> 5] >> (t & 31)) & 1;
      z[oo] = (bit ? 1.f : -1.f) - prs[b2 * 10 + oo];
      mx = fmaxf(mx, z[oo]);
    }
    float s = 0.f;
    #pragma unroll
    for (int oo = 0; oo < 10; ++oo) s += expf(z[oo] - mx);
    float ls = logf(s);
    float* op = out + (size_t)r * 10;       // r = t*16+b  ==  (t*NB+b)
    #pragma unroll
    for (int oo = 0; oo < 10; ++oo) op[oo] = z[oo] - mx - ls;
  }
}

// ---------------------------------------------------------------------------
extern "C" void kernel_launch(void* const* d_in, const int* in_sizes, int n_in,
                              void* d_out, int out_size, void* d_ws, size_t ws_size,
                              hipStream_t stream) {
  (void)in_sizes; (void)n_in; (void)out_size; (void)ws_size;
  const float* w1   = (const float*)d_in[0];
  const float* b1   = (const float*)d_in[1];
  const float* w2   = (const float*)d_in[2];
  const float* b2   = (const float*)d_in[3];
  const float* w3   = (const float*)d_in[4];
  const float* b3   = (const float*)d_in[5];
  const float* pred = (const float*)d_in[6];
  const int*   x    = (const int*)d_in[7];
  float* out = (float*)d_out;
  uint8_t* W = (uint8_t*)d_ws;

  uint32_t* T1   = (uint32_t*)(W + 0);          // 1 MB  [512 n][512 kp]
  uint32_t* T2   = (uint32_t*)(W + 1048576);    // 256 KB [256 n][256 kp]
  uint32_t* T3t  = (uint32_t*)(W + 1310720);    // 8 KB  [128 kp][10 n]
  uint32_t* bb1  = (uint32_t*)(W + 1318912);    // 16 KB
  uint32_t* bb2  = (uint32_t*)(W + 1335296);    // 8 KB
  uint32_t* bb3  = (uint32_t*)(W + 1343488);    // 512 B
  uint16_t* chks = (uint16_t*)(W + 1344000);    // 256 KB          end 1606144
  // V1 region (8 MB), dead after gemm1:
  uint16_t* V1   = (uint16_t*)(W + 1606144);
  uint16_t* Ys1  = (uint16_t*)(W + 1606144);    // 4 MB (alias, after gemm1)
  uint16_t* V2   = (uint16_t*)(W + 5800448);    // 4 MB
  // Yp region (16 MB max):
  uint8_t*  Yp1  = (uint8_t*) (W + 9994752);    // 8 x 2 MB u8
  uint8_t*  Yp2  = (uint8_t*) (W + 9994752);    // 4 x 1 MB u8 (alias)
  uint16_t* Ys2  = (uint16_t*)(W + 26771968);   // 2 MB
  uint16_t* V3   = (uint16_t*)(W + 28869120);   // 2 MB
  uint16_t* Y3   = (uint16_t*)(W + 30966272);   // 128 KB
  // peak end ~31 MB (proven available in R5-R8)

  hipLaunchKernelGGL(k_prepA, dim3(1822), dim3(256), 0, stream,
                     w1, w2, w3, b1, b2, b3, x, T1, T2, T3t, bb1, bb2, bb3, chks);
  hipLaunchKernelGGL(k_prep1, dim3(512), dim3(256), 0, stream, x, chks, V1);
  hipLaunchKernelGGL((k_gemmv4<1024, 512, 16, 128>), dim3(16, 32, 8), dim3(256),
                     0, stream, V1, T1, Yp1);
  hipLaunchKernelGGL(k_sumY, dim3(2048), dim3(256), 0, stream,
                     Yp1, Ys1, 512 * NM / 4, (size_t)(512 * NM / 4), 8);
  hipLaunchKernelGGL((k_scanv2<512, 1023, 9>), dim3(128), dim3(64), 0, stream,
                     Ys1, bb1, V2);
  hipLaunchKernelGGL((k_gemmv4<512, 256, 16, 128>), dim3(16, 16, 4), dim3(256),
                     0, stream, V2, T2, Yp2);
  hipLaunchKernelGGL(k_sumY, dim3(1024), dim3(256), 0, stream,
                     Yp2, Ys2, 256 * NM / 4, (size_t)(256 * NM / 4), 4);
  hipLaunchKernelGGL((k_scanv2<256, 511, 8>), dim3(64), dim3(64), 0, stream,
                     Ys2, bb2, V3);
  hipLaunchKernelGGL(k_l3, dim3(256), dim3(256), 0, stream, V3, T3t, Y3);
  hipLaunchKernelGGL(k_scan3sm, dim3(1), dim3(256), 0, stream, Y3, bb3, pred, out);
}

// Round 10
// 228.256 us; speedup vs baseline: 1.1233x; 1.0691x over previous
//
#include <hip/hip_runtime.h>
#include <stdint.h>

#define TSTEPS 256
#define NB 16
#define NM (TSTEPS*NB)   // 4096

typedef short s16x2 __attribute__((ext_vector_type(2)));

// perm(i) = bitrev8(gray(i)) : the Sobol value rng[i] = 2*perm8(i)/256 - 1
__device__ __forceinline__ uint32_t perm8(int i) {
  uint32_t g = (uint32_t)(i ^ (i >> 1));
  return __brev(g) >> 24;
}

// y = K + sum ashr16(a*t + e, 15): 3 separate asm insts so the scheduler can
// interleave independent chains; t2 is an SGPR (wave-uniform threshold pair).
__device__ __forceinline__ void qstep3s(uint32_t& acc, uint32_t t2, uint32_t a2,
                                        uint32_t e2, uint32_t c15) {
  uint32_t z, z2;
  asm("v_pk_mad_i16 %0, %1, %2, %3" : "=v"(z) : "v"(a2), "s"(t2), "v"(e2));
  asm("v_pk_ashrrev_i16 %0, %1, %2" : "=v"(z2) : "v"(c15), "v"(z));
  asm("v_pk_add_i16 %0, %0, %1" : "+v"(acc) : "v"(z2));
}

// all-VGPR variant (for l3 where T comes from LDS per-lane)
__device__ __forceinline__ void qstep3(uint32_t& acc, uint32_t t2, uint32_t a2,
                                       uint32_t e2, uint32_t c15) {
  uint32_t z;
  asm("v_pk_mad_i16 %0, %2, %3, %4\n\t"
      "v_pk_ashrrev_i16 %0, %5, %0\n\t"
      "v_pk_add_i16 %1, %1, %0"
      : "=&v"(z), "+v"(acc)
      : "v"(a2), "v"(t2), "v"(e2), "v"(c15));
}

__device__ __forceinline__ uint32_t pkadd16(uint32_t a, uint32_t b) {
  return __builtin_bit_cast(uint32_t,
        (s16x2)(__builtin_bit_cast(s16x2, a) + __builtin_bit_cast(s16x2, b)));
}

// unpack packed v16 (u | xbar<<15) pair -> (a2, e2)
__device__ __forceinline__ void unpackAE(uint32_t v2, uint32_t& a2, uint32_t& e2) {
  s16x2 sv = __builtin_bit_cast(s16x2, v2) >> 15;      // 0 / -1 per half (xbar)
  uint32_t su = __builtin_bit_cast(uint32_t, sv);
  uint32_t vand = v2 & 0x01FF01FFu;
  e2 = pkadd16(~vand, su & 0x01FF01FFu);   // x=1: ~u ; x=0: p' = 510-u
  a2 = pkadd16(0x00010001u, pkadd16(su, su));          // +1 / -1
}

__device__ __forceinline__ int rank256(float w) {
  double v = 128.0 * (double)w + 128.0;
  int t = (int)ceil(v);
  if (t < 0) t = 0; if (t > 256) t = 256;
  return t;
}

// ----------------- fused prep: rank tables + bias bitmasks + x chunk sums
// T1/T2 NATURAL layout: T[n][kp] (contiguous per-n rows for s_load).
__global__ __launch_bounds__(256) void k_prepA(
    const float* __restrict__ w1, const float* __restrict__ w2,
    const float* __restrict__ w3, const float* __restrict__ b1,
    const float* __restrict__ b2, const float* __restrict__ b3,
    const int* __restrict__ x,
    uint32_t* __restrict__ T1, uint32_t* __restrict__ T2,
    uint32_t* __restrict__ T3t, uint32_t* __restrict__ bb1,
    uint32_t* __restrict__ bb2, uint32_t* __restrict__ bb3,
    uint16_t* __restrict__ cs)
{
  int bid = blockIdx.x, tid = threadIdx.x;
  if (bid < 1024) {                      // w1 -> T1 [512 n][512 kp]
    int e = bid * 256 + tid;
    T1[e] = (uint32_t)rank256(w1[2 * e]) |
            ((uint32_t)rank256(w1[2 * e + 1]) << 16);
  } else if (bid < 1280) {               // w2 -> T2 [256 n][256 kp]
    int e = (bid - 1024) * 256 + tid;
    T2[e] = (uint32_t)rank256(w2[2 * e]) |
            ((uint32_t)rank256(w2[2 * e + 1]) << 16);
  } else if (bid < 1285) {               // w3 -> T3t [128 kp][10 n]
    int e = (bid - 1280) * 256 + tid;
    if (e < 1280) {
      int n = e % 10, kp = e / 10;
      T3t[e] = (uint32_t)rank256(w3[n * 256 + 2 * kp]) |
               ((uint32_t)rank256(w3[n * 256 + 2 * kp + 1]) << 16);
    }
  } else if (bid < 1301) {               // bb1: 512 o x 8 words
    int w = (bid - 1285) * 256 + tid;
    int o = w >> 3, j = w & 7;
    double bv = (double)b1[o] * 128.0 + 128.0;
    uint32_t bits = 0;
    for (int s = 0; s < 32; ++s)
      if (bv > (double)perm8(j * 32 + s)) bits |= 1u << s;
    bb1[w] = bits;
  } else if (bid < 1309) {               // bb2: 256 o x 8 words
    int w = (bid - 1301) * 256 + tid;
    int o = w >> 3, j = w & 7;
    double bv = (double)b2[o] * 128.0 + 128.0;
    uint32_t bits = 0;
    for (int s = 0; s < 32; ++s)
      if (bv > (double)perm8(j * 32 + s)) bits |= 1u << s;
    bb2[w] = bits;
  } else if (bid == 1309) {              // bb3: 10 o x 8 words
    if (tid < 80) {
      int o = tid >> 3, j = tid & 7;
      double bv = (double)b3[o] * 128.0 + 128.0;
      uint32_t bits = 0;
      for (int s = 0; s < 32; ++s)
        if (bv > (double)perm8(j * 32 + s)) bits |= 1u << s;
      bb3[tid] = bits;
    }
  } else {                               // x chunk sums (512 blocks)
    int g = (bid - 1310) * 256 + tid;
    int i = g & 1023, b = (g >> 10) & 15, c = g >> 14;
    int s = 0, t0 = c * 32;
    for (int tt = t0; tt < t0 + 32; ++tt)
      s += x[((size_t)tt * NB + b) * 1024 + i];
    cs[(c * NB + b) * 1024 + i] = (uint16_t)s;
  }
}

// -------------------------------- layer-1 V build (m = b*256+t, b-major)
__global__ __launch_bounds__(256) void k_prep1(const int* __restrict__ x,
                                               const uint16_t* __restrict__ cs,
                                               uint16_t* __restrict__ V1) {
  int g = blockIdx.x * 256 + threadIdx.x;
  int i = g & 1023, b = (g >> 10) & 15, c = g >> 14;
  int cum = 0;
  for (int cc = 0; cc < c; ++cc) cum += cs[(cc * NB + b) * 1024 + i];
  int t0 = c * 32;
  for (int tt = t0; tt < t0 + 32; ++tt) {
    int m = b * 256 + tt;
    int xv = x[((size_t)tt * NB + b) * 1024 + i];
    int idx = xv ? cum : (tt - cum);
    uint32_t p = perm8(idx);
    V1[(size_t)m * 1024 + i] =
        (uint16_t)((xv ? p : (510u - p)) | ((uint32_t)(xv ^ 1) << 15));
    cum += xv;
  }
}

// ---------------- k-outer binary GEMM: NREG n-accumulators resident,
// V unpacked ONCE per 8-element chunk. The asm volatile fence on the unpacked
// values pins them to a single execution per chunk — the compiler cannot
// slice the kernel per-n and rematerialize the V load (R9: that slicing made
// V traffic 16x redundant -> L2-BW-bound at 134us).
template<int KD, int NT, int NREG, int KC>
__global__ __launch_bounds__(256, 4) void k_gemmv4(
    const uint16_t* __restrict__ V, const uint32_t* __restrict__ T,
    uint8_t* __restrict__ Yp)
{
  const int tid = threadIdx.x;
  const int m = blockIdx.x * 256 + tid;
  const int n0 = blockIdx.y * NREG;
  const int sk = blockIdx.z;
  const int k0 = sk * KC;
  const uint32_t c15 = 0x000F000Fu;
  uint32_t acc[NREG];
  #pragma unroll
  for (int nn = 0; nn < NREG; ++nn) acc[nn] = 0;
  const uint4* vsrc = (const uint4*)(V + (size_t)m * KD + k0);
  const uint32_t* tbase = T + (size_t)n0 * (KD / 2) + (k0 >> 1);
  #pragma unroll 1
  for (int c = 0; c < KC / 8; ++c) {
    uint4 vv = vsrc[c];
    uint32_t a0, e0, a1, e1, a2v, e2v, a3, e3;
    unpackAE(vv.x, a0, e0);
    unpackAE(vv.y, a1, e1);
    unpackAE(vv.z, a2v, e2v);
    unpackAE(vv.w, a3, e3);
    // pin: one unpack per chunk, shared by all NREG accumulator chains
    asm volatile("" : "+v"(a0), "+v"(e0), "+v"(a1), "+v"(e1),
                      "+v"(a2v), "+v"(e2v), "+v"(a3), "+v"(e3));
    #pragma unroll
    for (int nn = 0; nn < NREG; ++nn) {
      uint4 tw = *(const uint4*)(tbase + (size_t)nn * (KD / 2) + c * 4);
      qstep3s(acc[nn], tw.x, a0, e0, c15);
      qstep3s(acc[nn], tw.y, a1, e1, c15);
      qstep3s(acc[nn], tw.z, a2v, e2v, c15);
      qstep3s(acc[nn], tw.w, a3, e3, c15);
    }
  }
  uint8_t* outp = Yp + ((size_t)sk * NT + n0) * (size_t)NM + m;
  #pragma unroll
  for (int nn = 0; nn < NREG; ++nn) {
    uint32_t s = acc[nn];
    int cnt = KC + (int)(short)(s & 0xFFFFu) + (int)(short)(s >> 16);
    outp[(size_t)nn * NM] = (uint8_t)cnt;
  }
}

// ------------------- sum SK u8 split-K planes -> u16 counts [n][m]
__global__ __launch_bounds__(256) void k_sumY(
    const uint8_t* __restrict__ Yp, uint16_t* __restrict__ Ys,
    int nwords, size_t plane_words, int SK)
{
  int i = blockIdx.x * 256 + threadIdx.x;
  if (i >= nwords) return;
  const uint32_t* p = (const uint32_t*)Yp;
  uint32_t aL = 0, aH = 0;
  for (int s = 0; s < SK; ++s) {
    uint32_t w = p[(size_t)s * plane_words + i];
    aL = pkadd16(aL, w & 0x00FF00FFu);
    aH = pkadd16(aH, (w >> 8) & 0x00FF00FFu);
  }
  uint2 o;
  o.x = (aL & 0xFFFFu) | (aH << 16);
  o.y = (aL >> 16) | (aH & 0xFFFF0000u);
  ((uint2*)Ys)[i] = o;
}

// ---------------- integer scan (ulinear + ucompare) -> next-layer V
template<int NOUT, int OFF2, int LOGN>
__global__ __launch_bounds__(64) void k_scanv2(
    const uint16_t* __restrict__ Ys, const uint32_t* __restrict__ bb,
    uint16_t* __restrict__ Vn)
{
  int g = blockIdx.x * 64 + threadIdx.x;
  int o = g & (NOUT - 1);
  int b = g >> LOGN;
  const uint16_t* row = Ys + (size_t)o * NM + b * 256;
  int in2 = 0, out2 = 0, c2 = 0, cum = 0;
  uint4 cur = *(const uint4*)row;
  #pragma unroll
  for (int w = 0; w < 8; ++w) {
    uint32_t bwc = bb[o * 8 + w];
    #pragma unroll
    for (int cchunk = 0; cchunk < 4; ++cchunk) {
      int t0 = w * 32 + cchunk * 8;
      uint4 nxt = cur;
      if (t0 < 248) nxt = *(const uint4*)(row + t0 + 8);
      uint32_t cw[4] = {cur.x, cur.y, cur.z, cur.w};
      #pragma unroll
      for (int j = 0; j < 8; ++j) {
        int t = t0 + j;
        int cnt = (int)((cw[j >> 1] >> ((j & 1) * 16)) & 0xFFFFu);
        int bit = (int)((bwc >> (t & 31)) & 1u);
        in2 += 2 * cnt + 2 * bit - OFF2;
        int outb = (in2 > out2) ? 1 : 0;
        out2 += outb << 1;
        int a = (c2 < 0) ? 1 : outb;
        c2 += (a << 2) - 2;
        int idx = a ? cum : (t - cum);
        cum += a;
        uint32_t p = perm8(idx);
        Vn[(size_t)(b * 256 + t) * NOUT + o] =
            (uint16_t)((a ? p : (510u - p)) | ((uint32_t)(a ^ 1) << 15));
      }
      cur = nxt;
    }
  }
}

// ------------------------------------------------------------ layer 3 (OUT=10)
__global__ __launch_bounds__(256) void k_l3(
    const uint16_t* __restrict__ V3, const uint32_t* __restrict__ T3t,
    uint16_t* __restrict__ y3)
{
  __shared__ uint32_t T3s[128][16];    // [kp][o]
  __shared__ uint32_t UFs3[16][258];   // [m][2*kp + {a,e}]
  int tid = threadIdx.x;
  int m0 = blockIdx.x * 16;
  const uint32_t c15 = 0x000F000Fu;
  for (int j = tid; j < 2048; j += 256) {
    int kp = j >> 4, o2 = j & 15;
    T3s[kp][o2] = (o2 < 10) ? T3t[kp * 10 + o2] : 0u;
  }
  { int row = tid >> 4, part = tid & 15;
    const uint4* src = (const uint4*)(V3 + (size_t)(m0 + row) * 256 + part * 16);
    uint4 pa = src[0], pb = src[1];
    uint32_t w[8] = {pa.x, pa.y, pa.z, pa.w, pb.x, pb.y, pb.z, pb.w};
    uint32_t o[16];
    #pragma unroll
    for (int q = 0; q < 8; ++q) unpackAE(w[q], o[q * 2], o[q * 2 + 1]);
    #pragma unroll
    for (int q4 = 0; q4 < 4; ++q4)
      *(uint4*)&UFs3[row][part * 16 + q4 * 4] =
          make_uint4(o[q4 * 4], o[q4 * 4 + 1], o[q4 * 4 + 2], o[q4 * 4 + 3]);
  }
  __syncthreads();
  int mr = tid >> 4, o = tid & 15;
  uint32_t acc = 0;
  #pragma unroll 4
  for (int kp2 = 0; kp2 < 64; ++kp2) {
    uint4 uf = *(const uint4*)&UFs3[mr][kp2 * 4];
    qstep3(acc, T3s[2 * kp2][o],     uf.x, uf.y, c15);
    qstep3(acc, T3s[2 * kp2 + 1][o], uf.z, uf.w, c15);
  }
  if (o < 10)
    y3[(size_t)(m0 + mr) * 16 + o] =
        (uint16_t)(256 + (short)(acc & 0xFFFFu) + (short)(acc >> 16));
}

// ---------------- layer-3 scan (bit-matrix in LDS) + log_softmax, fused
__global__ __launch_bounds__(256) void k_scan3sm(
    const uint16_t* __restrict__ y3, const uint32_t* __restrict__ bb3,
    const float* __restrict__ pred, float* __restrict__ out)
{
  __shared__ uint32_t obl[16][16][8];
  __shared__ float prs[160];
  int tid = threadIdx.x;
  if (tid < 160) prs[tid] = pred[tid];
  int b = tid >> 4, o = tid & 15;
  if (o < 10) {
    const uint16_t* row = y3 + (size_t)b * 256 * 16 + o;
    int in2 = 0, out2 = 0;
    #pragma unroll
    for (int w = 0; w < 8; ++w) {
      uint32_t bwc = bb3[o * 8 + w];
      uint32_t bits = 0;
      for (int s = 0; s < 32; ++s) {
        int cnt = row[(w * 32 + s) * 16];
        in2 += 2 * cnt + 2 * (int)((bwc >> s) & 1u) - 255;
        int outb = (in2 > out2) ? 1 : 0;
        out2 += outb << 1;
        bits |= (uint32_t)outb << s;
      }
      obl[b][o][w] = bits;
    }
  }
  __syncthreads();
  for (int r = tid; r < 4096; r += 256) {
    int t = r >> 4, b2 = r & 15;
    float z[10], mx = -3e38f;
    #pragma unroll
    for (int oo = 0; oo < 10; ++oo) {
      int bit = (obl[b2][oo][t >> 5] >> (t & 31)) & 1;
      z[oo] = (bit ? 1.f : -1.f) - prs[b2 * 10 + oo];
      mx = fmaxf(mx, z[oo]);
    }
    float s = 0.f;
    #pragma unroll
    for (int oo = 0; oo < 10; ++oo) s += expf(z[oo] - mx);
    float ls = logf(s);
    float* op = out + (size_t)r * 10;       // r = t*16+b  ==  (t*NB+b)
    #pragma unroll
    for (int oo = 0; oo < 10; ++oo) op[oo] = z[oo] - mx - ls;
  }
}

// ---------------------------------------------------------------------------
extern "C" void kernel_launch(void* const* d_in, const int* in_sizes, int n_in,
                              void* d_out, int out_size, void* d_ws, size_t ws_size,
                              hipStream_t stream) {
  (void)in_sizes; (void)n_in; (void)out_size; (void)ws_size;
  const float* w1   = (const float*)d_in[0];
  const float* b1   = (const float*)d_in[1];
  const float* w2   = (const float*)d_in[2];
  const float* b2   = (const float*)d_in[3];
  const float* w3   = (const float*)d_in[4];
  const float* b3   = (const float*)d_in[5];
  const float* pred = (const float*)d_in[6];
  const int*   x    = (const int*)d_in[7];
  float* out = (float*)d_out;
  uint8_t* W = (uint8_t*)d_ws;

  uint32_t* T1   = (uint32_t*)(W + 0);          // 1 MB  [512 n][512 kp]
  uint32_t* T2   = (uint32_t*)(W + 1048576);    // 256 KB [256 n][256 kp]
  uint32_t* T3t  = (uint32_t*)(W + 1310720);    // 8 KB  [128 kp][10 n]
  uint32_t* bb1  = (uint32_t*)(W + 1318912);    // 16 KB
  uint32_t* bb2  = (uint32_t*)(W + 1335296);    // 8 KB
  uint32_t* bb3  = (uint32_t*)(W + 1343488);    // 512 B
  uint16_t* chks = (uint16_t*)(W + 1344000);    // 256 KB          end 1606144
  // V1 region (8 MB), dead after gemm1:
  uint16_t* V1   = (uint16_t*)(W + 1606144);
  uint16_t* Ys1  = (uint16_t*)(W + 1606144);    // 4 MB (alias, after gemm1)
  uint16_t* V2   = (uint16_t*)(W + 5800448);    // 4 MB
  // Yp region (16 MB max):
  uint8_t*  Yp1  = (uint8_t*) (W + 9994752);    // 8 x 2 MB u8
  uint8_t*  Yp2  = (uint8_t*) (W + 9994752);    // 4 x 1 MB u8 (alias)
  uint16_t* Ys2  = (uint16_t*)(W + 26771968);   // 2 MB
  uint16_t* V3   = (uint16_t*)(W + 28869120);   // 2 MB
  uint16_t* Y3   = (uint16_t*)(W + 30966272);   // 128 KB
  // peak end ~31 MB (proven available in R5-R9)

  hipLaunchKernelGGL(k_prepA, dim3(1822), dim3(256), 0, stream,
                     w1, w2, w3, b1, b2, b3, x, T1, T2, T3t, bb1, bb2, bb3, chks);
  hipLaunchKernelGGL(k_prep1, dim3(512), dim3(256), 0, stream, x, chks, V1);
  hipLaunchKernelGGL((k_gemmv4<1024, 512, 16, 128>), dim3(16, 32, 8), dim3(256),
                     0, stream, V1, T1, Yp1);
  hipLaunchKernelGGL(k_sumY, dim3(2048), dim3(256), 0, stream,
                     Yp1, Ys1, 512 * NM / 4, (size_t)(512 * NM / 4), 8);
  hipLaunchKernelGGL((k_scanv2<512, 1023, 9>), dim3(128), dim3(64), 0, stream,
                     Ys1, bb1, V2);
  hipLaunchKernelGGL((k_gemmv4<512, 256, 16, 128>), dim3(16, 16, 4), dim3(256),
                     0, stream, V2, T2, Yp2);
  hipLaunchKernelGGL(k_sumY, dim3(1024), dim3(256), 0, stream,
                     Yp2, Ys2, 256 * NM / 4, (size_t)(256 * NM / 4), 4);
  hipLaunchKernelGGL((k_scanv2<256, 511, 8>), dim3(64), dim3(64), 0, stream,
                     Ys2, bb2, V3);
  hipLaunchKernelGGL(k_l3, dim3(256), dim3(256), 0, stream, V3, T3t, Y3);
  hipLaunchKernelGGL(k_scan3sm, dim3(1), dim3(256), 0, stream, Y3, bb3, pred, out);
}